// Round 4
// baseline (230.678 us; speedup 1.0000x reference)
//
#include <hip/hip_runtime.h>
#include <hip/hip_bf16.h>

// N=50000 nodes, E=800000 edges, D=96 (in = hidden = out)
#define NNODES 50000
#define NEDGES 800000
#define DIM    96
#define NBUCK  196      // ceil(N/256): bucket = dst >> 8
#define CAP    4608     // per-bucket capacity (mean 4096, sigma 64 -> +8 sigma)
#define TM     64       // rows per GEMM block
#define XPAD   104      // LDS row stride (bf16), 16B-aligned
#define PCH    3125     // edges per partition block (256 * 3125 = 800000)

typedef __attribute__((ext_vector_type(8))) short   short8;   // 8 bf16 = 4 VGPRs
typedef __attribute__((ext_vector_type(4))) float   float4v;  // MFMA acc

// flags[0] = 1 if float tensors are bf16, 0 if f32
// flags[1] = 1 if edge_index is int64, 0 if int32
__device__ __forceinline__ float loadF(const void* p, long i, int isbf) {
    return isbf ? __bfloat162float(((const __hip_bfloat16*)p)[i])
                : ((const float*)p)[i];
}
__device__ __forceinline__ int clampN(int v) {
    return v < 0 ? 0 : (v >= NNODES ? NNODES - 1 : v);
}
__device__ __forceinline__ int edgeDst(const int* w, int e, int is64) {
    return clampN(is64 ? w[2 * (NEDGES + e)] : w[NEDGES + e]);
}
__device__ __forceinline__ int edgeSrc(const int* w, int e, int is64) {
    return clampN(is64 ? w[2 * e] : w[e]);
}
// unpack 4 bf16 (as uint2) -> float4
__device__ __forceinline__ float4 unpack4(uint2 r) {
    __hip_bfloat162 lo = *(__hip_bfloat162*)&r.x;
    __hip_bfloat162 hi = *(__hip_bfloat162*)&r.y;
    float2 l2 = __bfloat1622float2(lo);
    float2 h2 = __bfloat1622float2(hi);
    float4 o; o.x = l2.x; o.y = l2.y; o.z = h2.x; o.w = h2.y;
    return o;
}

// single wave: sniff dtypes; zero the per-bucket cursors (replaces memsets)
__global__ void k_sniff(const unsigned* __restrict__ xw,
                        const unsigned* __restrict__ ew,
                        int* __restrict__ flags,
                        int* __restrict__ bcur) {
    int lane = threadIdx.x;
    for (int i = lane; i < NBUCK; i += 64) bcur[i] = 0;
    int bad = 0, nz = 0;
    for (int r = 0; r < 4; ++r) {
        unsigned w  = xw[lane + 64 * r];
        unsigned lo = w & 0xffffu;
        unsigned ex = (lo >> 7) & 0xffu;
        if (!(lo == 0u || (ex >= 90u && ex <= 145u))) bad++;
        unsigned o = ew[2 * (lane + 64 * r) + 1];
        if (o != 0u) nz++;
    }
    for (int off = 32; off; off >>= 1) {
        bad += __shfl_down(bad, off);
        nz  += __shfl_down(nz,  off);
    }
    if (lane == 0) {
        flags[0] = (bad <= 32) ? 1 : 0;
        flags[1] = (nz  <  4) ? 1 : 0;
    }
}

// partition edges into FIXED-CAPACITY bucket regions (no counting pass, no
// scan): decode once into LDS, LDS histogram, reserve [base, base+c) in the
// bucket's padded region via one atomicAdd on bcur, scatter from LDS.
__global__ __launch_bounds__(256) void k_part(const int* __restrict__ w,
                                              int* __restrict__ bcur,
                                              unsigned* __restrict__ ebuf,
                                              const int* __restrict__ flags) {
    __shared__ unsigned pack[PCH];   // 12.5 KB: this block's packed edges
    __shared__ int h[NBUCK];
    __shared__ int base[NBUCK];
    const int is64 = flags[1];
    const int tid  = threadIdx.x;
    const int e0   = blockIdx.x * PCH;

    for (int i = tid; i < NBUCK; i += 256) h[i] = 0;
    __syncthreads();
    for (int k = tid; k < PCH; k += 256) {
        int e = e0 + k;
        int s = edgeSrc(w, e, is64);
        int d = edgeDst(w, e, is64);
        pack[k] = ((unsigned)d << 16) | (unsigned)s;
        atomicAdd(&h[d >> 8], 1);
    }
    __syncthreads();
    for (int i = tid; i < NBUCK; i += 256) {
        int c = h[i];
        base[i] = c ? i * CAP + atomicAdd(&bcur[i], c) : 0;
        h[i] = 0;                    // reuse as local cursor
    }
    __syncthreads();
    for (int k = tid; k < PCH; k += 256) {
        unsigned r = pack[k];
        int b = r >> 24;             // dst >> 8
        int pos = base[b] + atomicAdd(&h[b], 1);
        if (pos < (b + 1) * CAP) ebuf[pos] = r;   // overflow guard (never hit)
    }
}

// per-bucket local CSR (512 threads): histogram 256 local dsts, scan ->
// rowbeg/rowend/dinv in PADDED coordinates, LDS-cursor scatter of col (u16).
__global__ __launch_bounds__(512) void k_csr(const unsigned* __restrict__ ebuf,
                                             const int* __restrict__ bcur,
                                             int* __restrict__ rowbeg,
                                             int* __restrict__ rowend,
                                             unsigned short* __restrict__ col,
                                             float* __restrict__ dinv) {
    __shared__ int h256[256];
    __shared__ int sc[256];
    __shared__ int cur[256];
    const int b   = blockIdx.x;
    const int tid = threadIdx.x;
    int cnt = bcur[b]; if (cnt > CAP) cnt = CAP;
    const int e0 = b * CAP;
    const int e1 = e0 + cnt;

    if (tid < 256) h256[tid] = 0;
    __syncthreads();
    for (int e = e0 + tid; e < e1; e += 512)
        atomicAdd(&h256[(ebuf[e] >> 16) & 255], 1);
    __syncthreads();
    int v = 0;
    if (tid < 256) { v = h256[tid]; sc[tid] = v; }
    __syncthreads();
    for (int off = 1; off < 256; off <<= 1) {
        int t2 = 0;
        if (tid < 256 && tid >= off) t2 = sc[tid - off];
        __syncthreads();
        if (tid < 256) sc[tid] += t2;
        __syncthreads();
    }
    if (tid < 256) {
        int start = e0 + sc[tid] - v;    // exclusive, padded coordinates
        cur[tid] = start;
        int node = b * 256 + tid;
        if (node < NNODES) {
            rowbeg[node] = start;
            rowend[node] = start + v;
            dinv[node] = rsqrtf((float)v + 1.0f);   // +1 self loop
        }
    }
    __syncthreads();
    for (int e = e0 + tid; e < e1; e += 512) {
        unsigned r = ebuf[e];
        int pos = atomicAdd(&cur[(r >> 16) & 255], 1);
        col[pos] = (unsigned short)(r & 0xffffu);
    }
}

// MFMA GEMM: g[row,:] = bf16( dinv[row] * (X[row,:] @ W) )
// block = 256 (4 waves), 64 rows/block; X strip + W^T staged in LDS as bf16.
__global__ __launch_bounds__(256) void k_gemm_mfma(
        const void* __restrict__ X, int x_force_bf16,
        const void* __restrict__ W,
        const float* __restrict__ dinv,
        __hip_bfloat16* __restrict__ g,
        const int* __restrict__ flags) {
    __shared__ __hip_bfloat16 Xs[TM * XPAD];
    __shared__ __hip_bfloat16 Wt[DIM * XPAD];

    const int t    = threadIdx.x;
    const int fbf  = flags[0];
    const int xbf  = x_force_bf16 ? 1 : fbf;
    const int row0 = blockIdx.x * TM;

    // stage W^T (vectorized when f32)
    if (!fbf) {
        const float4* Wv = (const float4*)W;
        for (int idx = t; idx < DIM * DIM / 4; idx += 256) {
            int k = idx / (DIM / 4);
            int n = (idx - k * (DIM / 4)) * 4;
            float4 w4 = Wv[idx];
            Wt[(n + 0) * XPAD + k] = __float2bfloat16(w4.x);
            Wt[(n + 1) * XPAD + k] = __float2bfloat16(w4.y);
            Wt[(n + 2) * XPAD + k] = __float2bfloat16(w4.z);
            Wt[(n + 3) * XPAD + k] = __float2bfloat16(w4.w);
        }
    } else {
        for (int idx = t; idx < DIM * DIM; idx += 256) {
            int k = idx / DIM, n = idx - k * DIM;
            Wt[n * XPAD + k] = __float2bfloat16(loadF(W, idx, 1));
        }
    }
    // stage X strip (vectorized both paths)
    if (!xbf) {
        const float4* Xv = (const float4*)X;
        for (int idx = t; idx < TM * (DIM / 4); idx += 256) {
            int r = idx / (DIM / 4);
            int c = (idx - r * (DIM / 4)) * 4;
            int gr = row0 + r;
            float4 vv = {0.f, 0.f, 0.f, 0.f};
            if (gr < NNODES) vv = Xv[(size_t)gr * (DIM / 4) + (c >> 2)];
            *(__hip_bfloat162*)&Xs[r * XPAD + c] =
                __halves2bfloat162(__float2bfloat16(vv.x), __float2bfloat16(vv.y));
            *(__hip_bfloat162*)&Xs[r * XPAD + c + 2] =
                __halves2bfloat162(__float2bfloat16(vv.z), __float2bfloat16(vv.w));
        }
    } else {
        const short* Xs16 = (const short*)X;
        for (int idx = t; idx < TM * (DIM / 8); idx += 256) {
            int r  = idx / (DIM / 8);
            int c8 = idx - r * (DIM / 8);
            int gr = row0 + r;
            short8 vv = {0, 0, 0, 0, 0, 0, 0, 0};
            if (gr < NNODES) vv = *(const short8*)(Xs16 + (size_t)gr * DIM + c8 * 8);
            *(short8*)((short*)Xs + r * XPAD + c8 * 8) = vv;
        }
    }
    __syncthreads();

    const int wave = t >> 6;
    const int lane = t & 63;
    const int m    = lane & 15;
    const int quad = lane >> 4;

    const short* xsp = (const short*)Xs;
    short8 a[3];
#pragma unroll
    for (int kt = 0; kt < 3; ++kt)
        a[kt] = *(const short8*)(xsp + (wave * 16 + m) * XPAD + kt * 32 + quad * 8);

    float dv[4];
#pragma unroll
    for (int r2 = 0; r2 < 4; ++r2) {
        int gr = row0 + wave * 16 + quad * 4 + r2;
        dv[r2] = (gr < NNODES) ? dinv[gr] : 0.f;
    }

    const short* wtp = (const short*)Wt;
#pragma unroll
    for (int nt = 0; nt < 6; ++nt) {
        float4v acc = {0.f, 0.f, 0.f, 0.f};
#pragma unroll
        for (int kt = 0; kt < 3; ++kt) {
            short8 b = *(const short8*)(wtp + (nt * 16 + m) * XPAD + kt * 32 + quad * 8);
            acc = __builtin_amdgcn_mfma_f32_16x16x32_bf16(a[kt], b, acc, 0, 0, 0);
        }
#pragma unroll
        for (int r2 = 0; r2 < 4; ++r2) {
            int gr = row0 + wave * 16 + quad * 4 + r2;
            if (gr < NNODES)
                g[(size_t)gr * DIM + nt * 16 + m] = __float2bfloat16(acc[r2] * dv[r2]);
        }
    }
}

// aggregate + epilogue: TWO rows per wave. Lanes 0..23 gather for row A,
// lanes 24..47 for row B; each lane loads 8B (4 bf16 = 4 columns) per
// gather -> 384B / 2 neighbors per VMEM instruction (half the issue count
// of the 4B/lane scheme). Predicated clamp tail; 8 gathers in flight/row.
__global__ __launch_bounds__(256) void k_aggr(
        const __hip_bfloat16* __restrict__ g,
        const int* __restrict__ rowbeg,
        const int* __restrict__ rowend,
        const unsigned short* __restrict__ col,
        const float* __restrict__ dinv,
        const void* __restrict__ b,
        const void* __restrict__ a1,
        void* __restrict__ out,
        const int* __restrict__ flags, int prelu) {
    const int wave = threadIdx.x >> 6;
    const int lane = threadIdx.x & 63;
    const int rowA = blockIdx.x * 8 + wave * 2;      // 8 rows per block
    if (rowA >= NNODES) return;                      // wave-uniform
    const int rowB  = rowA + 1;
    const int hasB  = rowB < NNODES;
    const int half  = lane >= 24;                    // 1 -> row B
    const int sub   = half ? lane - 24 : lane;       // 0..23 (4 cols each)
    const bool act  = (lane < 48) && (!half || hasB);
    const int myrow = half ? rowB : rowA;
    const int fbf   = flags[0];

    const uint2* gv2 = (const uint2*)g;              // 8B = 4 bf16 cols

    float4 acc = {0.f, 0.f, 0.f, 0.f};
    if (act) acc = unpack4(gv2[(size_t)myrow * 24 + sub]);   // self loop

    const int pA0 = rowbeg[rowA];
    const int degA = rowend[rowA] - pA0;
    int pB0 = pA0, degB = 0;
    if (hasB) { pB0 = rowbeg[rowB]; degB = rowend[rowB] - pB0; }
    const int pM0  = half ? pB0 : pA0;
    const int degM = half ? degB : degA;
    const int maxd = degA > degB ? degA : degB;

    for (int j0 = 0; j0 < maxd; j0 += 8) {
        int sA[8], sB[8];
#pragma unroll
        for (int k = 0; k < 8; ++k) {
            int jA = j0 + k; jA = jA >= degA ? degA - 1 : jA; jA = jA < 0 ? 0 : jA;
            int jB = j0 + k; jB = jB >= degB ? degB - 1 : jB; jB = jB < 0 ? 0 : jB;
            sA[k] = col[pA0 + jA];
            sB[k] = hasB ? col[pB0 + jB] : 0;
        }
        if (act) {
            float4 v[8];
#pragma unroll
            for (int k = 0; k < 8; ++k) {
                int s = half ? sB[k] : sA[k];
                v[k] = unpack4(gv2[(size_t)s * 24 + sub]);
                if (j0 + k >= degM) { v[k].x = 0.f; v[k].y = 0.f; v[k].z = 0.f; v[k].w = 0.f; }
            }
            float4 t0, t1;
            t0.x = (v[0].x + v[1].x) + (v[2].x + v[3].x);
            t0.y = (v[0].y + v[1].y) + (v[2].y + v[3].y);
            t0.z = (v[0].z + v[1].z) + (v[2].z + v[3].z);
            t0.w = (v[0].w + v[1].w) + (v[2].w + v[3].w);
            t1.x = (v[4].x + v[5].x) + (v[6].x + v[7].x);
            t1.y = (v[4].y + v[5].y) + (v[6].y + v[7].y);
            t1.z = (v[4].z + v[5].z) + (v[6].z + v[7].z);
            t1.w = (v[4].w + v[5].w) + (v[6].w + v[7].w);
            acc.x += t0.x + t1.x;
            acc.y += t0.y + t1.y;
            acc.z += t0.z + t1.z;
            acc.w += t0.w + t1.w;
        }
    }
    (void)pM0;

    if (act) {
        float dv = dinv[myrow];
        float v0 = dv * acc.x + loadF(b, 4 * sub,     fbf);
        float v1 = dv * acc.y + loadF(b, 4 * sub + 1, fbf);
        float v2 = dv * acc.z + loadF(b, 4 * sub + 2, fbf);
        float v3 = dv * acc.w + loadF(b, 4 * sub + 3, fbf);
        if (prelu) {
            float alpha = loadF(a1, 0, fbf);
            v0 = v0 > 0.f ? v0 : alpha * v0;
            v1 = v1 > 0.f ? v1 : alpha * v1;
            v2 = v2 > 0.f ? v2 : alpha * v2;
            v3 = v3 > 0.f ? v3 : alpha * v3;
        }
        if (prelu || fbf) {
            uint2 o;
            __hip_bfloat162 lo = __halves2bfloat162(__float2bfloat16(v0), __float2bfloat16(v1));
            __hip_bfloat162 hi = __halves2bfloat162(__float2bfloat16(v2), __float2bfloat16(v3));
            o.x = *(unsigned*)&lo; o.y = *(unsigned*)&hi;
            ((uint2*)out)[(size_t)myrow * 24 + sub] = o;
        } else {
            float4 o; o.x = v0; o.y = v1; o.z = v2; o.w = v3;
            ((float4*)out)[(size_t)myrow * 24 + sub] = o;
        }
    }
}

extern "C" void kernel_launch(void* const* d_in, const int* in_sizes, int n_in,
                              void* d_out, int out_size, void* d_ws, size_t ws_size,
                              hipStream_t stream) {
    const void* x  = d_in[0];
    const int*  ei = (const int*)d_in[1];
    const void* W1 = d_in[2];
    const void* b1 = d_in[3];
    const void* a1 = d_in[4];
    const void* W2 = d_in[5];
    const void* b2 = d_in[6];

    size_t off = 0;
    auto alloc = [&](size_t bytes) { size_t p = off; off = (off + bytes + 255) & ~(size_t)255; return p; };
    char* ws = (char*)d_ws;
    int*            flags  = (int*)           (ws + alloc(1024));
    float*          dinv   = (float*)         (ws + alloc((size_t)NNODES * 4));
    int*            bcur   = (int*)           (ws + alloc((size_t)NBUCK * 4));
    int*            rowbeg = (int*)           (ws + alloc((size_t)NNODES * 4));
    int*            rowend = (int*)           (ws + alloc((size_t)NNODES * 4));
    unsigned*       ebuf   = (unsigned*)      (ws + alloc((size_t)NBUCK * CAP * 4));
    unsigned short* col    = (unsigned short*)(ws + alloc((size_t)NBUCK * CAP * 2 + 256));
    __hip_bfloat16* g      = (__hip_bfloat16*)(ws + alloc((size_t)NNODES * DIM * 2));
    __hip_bfloat16* g2     = (__hip_bfloat16*)(ws + alloc((size_t)NNODES * DIM * 2));
    if (ws_size < off) return;   // ~25.5 MiB

    // ---- CSR build: padded-bucket counting sort, single edge pass --------
    k_sniff<<<1, 64, 0, stream>>>((const unsigned*)x, (const unsigned*)ei, flags, bcur);
    k_part <<<256, 256, 0, stream>>>(ei, bcur, ebuf, flags);
    k_csr  <<<NBUCK, 512, 0, stream>>>(ebuf, bcur, rowbeg, rowend, col, dinv);

    const int gemm_grid = (NNODES + TM - 1) / TM;       // 782
    const int aggr_grid = (NNODES + 7) / 8;             // 6250 (8 rows/block)

    // ---- layer 1 ----
    k_gemm_mfma<<<gemm_grid, 256, 0, stream>>>(x, 0, W1, dinv, g, flags);
    k_aggr<<<aggr_grid, 256, 0, stream>>>(g, rowbeg, rowend, col, dinv, b1, a1, g2, flags, 1);

    // ---- layer 2 ----
    k_gemm_mfma<<<gemm_grid, 256, 0, stream>>>(g2, 1, W2, dinv, g, flags);
    k_aggr<<<aggr_grid, 256, 0, stream>>>(g, rowbeg, rowend, col, dinv, b2, a1, d_out, flags, 0);
}